// Round 19
// baseline (260.689 us; speedup 1.0000x reference)
//
#include <hip/hip_runtime.h>
#include <hip/hip_bf16.h>
#include <math.h>

static constexpr int kN = 8192;
static constexpr int kD = 384;
static constexpr int kND = kN * kD;

typedef __attribute__((ext_vector_type(8))) short short8;
typedef __attribute__((ext_vector_type(4))) float f32x4;

// ---- bf16 helpers (bit-exact RNE) ----
__device__ __forceinline__ ushort f2bf(float f) {
  union { float f; unsigned int i; } cv; cv.f = f;
  unsigned int lsb = (cv.i >> 16) & 1u;
  unsigned int r = cv.i + 0x7fffu + lsb;
  return (ushort)(r >> 16);
}
__device__ __forceinline__ float bf2f(ushort u) {
  union { unsigned int i; float f; } cv; cv.i = ((unsigned int)u) << 16;
  return cv.f;
}
__device__ __forceinline__ f32x4 mfma_bf16(short8 a, short8 b, f32x4 c) {
  return __builtin_amdgcn_mfma_f32_16x16x32_bf16(a, b, c, 0, 0, 0);
}
// LDS-only barrier: drains LDS ops for cross-wave visibility; in-flight
// global loads survive (no vmcnt(0) drain).
__device__ __forceinline__ void bar_lds() {
  asm volatile("s_waitcnt lgkmcnt(0)" ::: "memory");
  __builtin_amdgcn_s_barrier();
}

// ---------------------------------------------------------------------------
// g = Wv^T . ffws  (inputs-only; launched FIRST so it overlaps proj/flash).
// g[d] = sum_t ffws[t] * Wv[t][d];  6 blocks x 64 threads, coalesced over d.
// ---------------------------------------------------------------------------
__global__ __launch_bounds__(64) void gv_kernel(
    const float* __restrict__ Wv, const float* __restrict__ ffws,
    float* __restrict__ g)
{
  const int d = blockIdx.x * 64 + threadIdx.x;
  float acc = 0.f;
  for (int t = 0; t < kD; ++t) acc += ffws[t] * Wv[(size_t)t * kD + d];
  g[d] = acc;
}

// ---------------------------------------------------------------------------
// MFMA projection, 1-term bf16 (outputs are rounded to bf16 anyway).
// Single pass over x:
//   Qh = bf16(x@Wq^T), Kh = bf16(x@Wk^T)   (row-major [N][D])
//   VTh = bf16((x@Wv^T)^T)                  ([D][N])
// Block: 512 thr (8 waves), tile 128 rows x 96 cols, d-loop 12x32.
// LDS: XH 128x32 + WH 3x96x32 bf16 = 26 KB.
// ---------------------------------------------------------------------------
__global__ __launch_bounds__(512) void proj_mfma(
    const float* __restrict__ x, const float* __restrict__ Wq,
    const float* __restrict__ Wk, const float* __restrict__ Wv,
    ushort* __restrict__ Qh, ushort* __restrict__ Kh,
    ushort* __restrict__ VTh)
{
  __shared__ ushort XH[128 * 32];
  __shared__ ushort WH[3][96 * 32];

  const int tid = threadIdx.x;
  const int w = tid >> 6;
  const int lane = tid & 63;
  const int l15 = lane & 15;
  const int hi4 = lane >> 4;
  const int i0 = blockIdx.x * 128;
  const int j0 = blockIdx.y * 96;
  const float* Wm[3] = {Wq, Wk, Wv};

  const f32x4 zf = {0.f, 0.f, 0.f, 0.f};
  f32x4 acc[3][6];
#pragma unroll
  for (int m = 0; m < 3; ++m)
#pragma unroll
    for (int ct = 0; ct < 6; ++ct) acc[m][ct] = zf;

  const int xrow = tid >> 2;
  const int xc8 = (tid & 3) * 8;

  for (int dc = 0; dc < 12; ++dc) {
    const int d0 = dc * 32;
    {
      const float* src = x + (size_t)(i0 + xrow) * kD + d0 + xc8;
      const float4 v0 = *reinterpret_cast<const float4*>(src);
      const float4 v1 = *reinterpret_cast<const float4*>(src + 4);
      const float vs[8] = {v0.x, v0.y, v0.z, v0.w, v1.x, v1.y, v1.z, v1.w};
      ushort hh[8];
#pragma unroll
      for (int j = 0; j < 8; ++j) hh[j] = f2bf(vs[j]);
      *reinterpret_cast<uint4*>(&XH[xrow * 32 + xc8]) =
          *reinterpret_cast<const uint4*>(hh);
    }
    if (tid < 384) {
#pragma unroll
      for (int m = 0; m < 3; ++m) {
        const float* src = Wm[m] + (size_t)(j0 + xrow) * kD + d0 + xc8;
        const float4 v0 = *reinterpret_cast<const float4*>(src);
        const float4 v1 = *reinterpret_cast<const float4*>(src + 4);
        const float vs[8] = {v0.x, v0.y, v0.z, v0.w, v1.x, v1.y, v1.z, v1.w};
        ushort hh[8];
#pragma unroll
        for (int j = 0; j < 8; ++j) hh[j] = f2bf(vs[j]);
        *reinterpret_cast<uint4*>(&WH[m][xrow * 32 + xc8]) =
            *reinterpret_cast<const uint4*>(hh);
      }
    }
    __syncthreads();
    const short8 xa = *reinterpret_cast<const short8*>(
        &XH[(16 * w + l15) * 32 + 8 * hi4]);
#pragma unroll
    for (int m = 0; m < 3; ++m) {
#pragma unroll
      for (int ct = 0; ct < 6; ++ct) {
        const short8 wh = *reinterpret_cast<const short8*>(
            &WH[m][(16 * ct + l15) * 32 + 8 * hi4]);
        acc[m][ct] = mfma_bf16(xa, wh, acc[m][ct]);
      }
    }
    __syncthreads();
  }

#pragma unroll
  for (int ct = 0; ct < 6; ++ct)
#pragma unroll
    for (int r = 0; r < 4; ++r) {
      const size_t oi =
          (size_t)(i0 + 16 * w + 4 * hi4 + r) * kD + j0 + 16 * ct + l15;
      Qh[oi] = f2bf(acc[0][ct][r]);
      Kh[oi] = f2bf(acc[1][ct][r]);
    }
#pragma unroll
  for (int ct = 0; ct < 6; ++ct) {
    ushort4 h;
    ushort* hp = &h.x;
#pragma unroll
    for (int r = 0; r < 4; ++r) hp[r] = f2bf(acc[2][ct][r]);
    *reinterpret_cast<ushort4*>(
        &VTh[(size_t)(j0 + 16 * ct + l15) * kN + i0 + 16 * w + 4 * hi4]) = h;
  }
}

// ---------------------------------------------------------------------------
// MFMA flash attention v16 (best measured: 180.5 us, no spill): r11 schedule
// with vv issued IMMEDIATELY after the S-MFMAs (ka dead there -> register
// peak unchanged), so the V stream hides under max-reduce + B1 + softmax.
// BM=128, 512 threads (8 waves), SPLIT=4 -> grid (4,64)=256 blocks, 1/CU.
// Pure-bf16 S = kh*qh; P hi LDS; vectorized MLB; normalized bf16 Opart.
// Only ONE 12-frag stream buffer live at a time (128 arch-VGPR half;
// o[96]+sacc[32] fill the 128-AGPR half exactly).
// LDS: Qh 100K | P 34.8K | MLB 8K = 143K.
// ---------------------------------------------------------------------------
static constexpr int SPLITf = 4;
static constexpr int KEYSf = kN / SPLITf;   // 2048
static constexpr int NTIL = KEYSf / 128;    // 16

static constexpr int OFF_QH = 0;        // ushort offsets into LDSU
static constexpr int OFF_P  = 50176;    // 128*392

__global__ __launch_bounds__(512, 2) void flash_mfma(
    const ushort* __restrict__ Qh,
    const ushort* __restrict__ Kh,
    const ushort* __restrict__ VTh,
    ushort* __restrict__ Opart, float* __restrict__ ml)
{
  __shared__ ushort LDSU[67584];   // 135168 B (Qh 128x392 | P 128x136)
  __shared__ float MLB[2048];      // m: [(row)*8+w], l: 1024 + same

  const int tid = threadIdx.x;
  const int w = tid >> 6;
  const int lane = tid & 63;
  const int l15 = lane & 15;
  const int hi4 = lane >> 4;
  const int sp = blockIdx.x;
  const int i0 = blockIdx.y * 128;
  const int kg0 = sp * KEYSf;

  // ---- stage Q-hi once: 128 rows, stride 392 ushorts ----
  {
    const int row = tid >> 2;            // 0..127
    const int sg = (tid & 3) * 96;       // 96 ushorts = 12 x uint4
    const ushort* sh = Qh + (size_t)(i0 + row) * kD + sg;
    ushort* dh = LDSU + OFF_QH + row * 392 + sg;
#pragma unroll
    for (int u = 0; u < 12; ++u)
      *reinterpret_cast<uint4*>(dh + 8 * u) =
          *reinterpret_cast<const uint4*>(sh + 8 * u);
  }

  const f32x4 zf = {0.f, 0.f, 0.f, 0.f};
  f32x4 o[8][3];
#pragma unroll
  for (int qt = 0; qt < 8; ++qt)
#pragma unroll
    for (int c = 0; c < 3; ++c) o[qt][c] = zf;
  float m_run[8], l_run[8];
#pragma unroll
  for (int qt = 0; qt < 8; ++qt) { m_run[qt] = -INFINITY; l_run[qt] = 0.f; }

  __syncthreads();   // Q staged

  for (int kb = 0; kb < NTIL; ++kb) {
    const int kg = kg0 + kb * 128;

    // ---- S phase: K hi batch-loaded (12 frags), Q hi from LDS ----
    f32x4 sacc[8];
#pragma unroll
    for (int qt = 0; qt < 8; ++qt) sacc[qt] = zf;
    const size_t kbase = (size_t)(kg + 16 * w + l15) * kD + 8 * hi4;
    short8 ka[12];
#pragma unroll
    for (int ks = 0; ks < 12; ++ks)
      ka[ks] = *reinterpret_cast<const short8*>(Kh + kbase + 32 * ks);
    __builtin_amdgcn_sched_barrier(0);   // keep loads batched above MFMAs
#pragma unroll
    for (int ks = 0; ks < 12; ++ks) {
      const int d0 = 32 * ks;
#pragma unroll
      for (int qt = 0; qt < 8; ++qt) {
        const short8 qh = *reinterpret_cast<const short8*>(
            LDSU + OFF_QH + (16 * qt + l15) * 392 + d0 + 8 * hi4);
        sacc[qt] = mfma_bf16(ka[ks], qh, sacc[qt]);
      }
    }
    __builtin_amdgcn_sched_barrier(0);

    // ---- V-EARLIEST: issue 12 V-frag loads right after S (ka dead) ----
    // Stream hides under max-reduce + B1 barrier wait + softmax.
    short8 vv[12];
#pragma unroll
    for (int c = 0; c < 3; ++c)
#pragma unroll
      for (int kv = 0; kv < 4; ++kv)
        vv[c * 4 + kv] = *reinterpret_cast<const short8*>(
            VTh + (size_t)(48 * w + 16 * c + l15) * kN + kg + 32 * kv + 8 * hi4);
    __builtin_amdgcn_sched_barrier(0);

    // ---- per-wave tile max -> MLB (vector-friendly layout) ----
#pragma unroll
    for (int qt = 0; qt < 8; ++qt) {
      float mt = fmaxf(fmaxf(sacc[qt][0], sacc[qt][1]),
                       fmaxf(sacc[qt][2], sacc[qt][3]));
      mt = fmaxf(mt, __shfl_xor(mt, 16, 64));
      mt = fmaxf(mt, __shfl_xor(mt, 32, 64));
      if (lane < 16) MLB[(qt * 16 + l15) * 8 + w] = mt;
    }
    bar_lds();  // B1: all waves' m published

    // ---- softmax (vectorized MLB reads) ----
    float sc[8];
#pragma unroll
    for (int qt = 0; qt < 8; ++qt) {
      const float4 ma =
          *reinterpret_cast<const float4*>(&MLB[(qt * 16 + l15) * 8]);
      const float4 mb =
          *reinterpret_cast<const float4*>(&MLB[(qt * 16 + l15) * 8 + 4]);
      const float Mt = fmaxf(fmaxf(fmaxf(ma.x, ma.y), fmaxf(ma.z, ma.w)),
                             fmaxf(fmaxf(mb.x, mb.y), fmaxf(mb.z, mb.w)));
      const float mnew = fmaxf(m_run[qt], Mt);
      sc[qt] = __expf(m_run[qt] - mnew);
      m_run[qt] = mnew;
      const float p0 = __expf(sacc[qt][0] - mnew);
      const float p1 = __expf(sacc[qt][1] - mnew);
      const float p2 = __expf(sacc[qt][2] - mnew);
      const float p3 = __expf(sacc[qt][3] - mnew);
      float ls = (p0 + p1) + (p2 + p3);
      ls += __shfl_xor(ls, 16, 64);
      ls += __shfl_xor(ls, 32, 64);
      if (lane < 16) MLB[1024 + (qt * 16 + l15) * 8 + w] = ls;
      // pack P -> bf16 hi, one b64 write
      uint2 HH;
      HH.x = (unsigned int)f2bf(p0) | ((unsigned int)f2bf(p1) << 16);
      HH.y = (unsigned int)f2bf(p2) | ((unsigned int)f2bf(p3) << 16);
      const int pi = (16 * qt + l15) * 136 + 16 * w + 4 * hi4;
      *reinterpret_cast<uint2*>(LDSU + OFF_P + pi) = HH;
      // rescale O (row of o = qrow 16qt+4*hi4+r)
#pragma unroll
      for (int r = 0; r < 4; ++r) {
        const float scr_ = __shfl(sc[qt], 4 * hi4 + r, 64);
#pragma unroll
        for (int c = 0; c < 3; ++c) o[qt][c][r] *= scr_;
      }
    }
    bar_lds();  // B2: P + l published
#pragma unroll
    for (int qt = 0; qt < 8; ++qt) {
      const float4 la =
          *reinterpret_cast<const float4*>(&MLB[1024 + (qt * 16 + l15) * 8]);
      const float4 lb =
          *reinterpret_cast<const float4*>(&MLB[1024 + (qt * 16 + l15) * 8 + 4]);
      const float ls = ((la.x + la.y) + (la.z + la.w)) +
                       ((lb.x + lb.y) + (lb.z + lb.w));
      l_run[qt] = l_run[qt] * sc[qt] + ls;
    }

    // ---- PV: 96 MFMAs on prefetched vv ----
#pragma unroll
    for (int kv = 0; kv < 4; ++kv) {
      short8 pf[8];
#pragma unroll
      for (int qt = 0; qt < 8; ++qt)
        pf[qt] = *reinterpret_cast<const short8*>(
            LDSU + OFF_P + (16 * qt + l15) * 136 + 32 * kv + 8 * hi4);
#pragma unroll
      for (int c = 0; c < 3; ++c) {
#pragma unroll
        for (int qt = 0; qt < 8; ++qt)
          o[qt][c] = mfma_bf16(pf[qt], vv[c * 4 + kv], o[qt][c]);
      }
    }
  }

  // ---- write NORMALIZED bf16 partials + (m,l) ----
#pragma unroll
  for (int qt = 0; qt < 8; ++qt) {
    const float linv = 1.0f / l_run[qt];
#pragma unroll
    for (int r = 0; r < 4; ++r) {
      const float lr = __shfl(linv, 4 * hi4 + r, 64);
#pragma unroll
      for (int c = 0; c < 3; ++c)
        Opart[(size_t)sp * kND + (i0 + 16 * qt + 4 * hi4 + r) * kD +
              48 * w + 16 * c + l15] = f2bf(o[qt][c][r] * lr);
    }
  }
  if (w == 0 && lane < 16) {
#pragma unroll
    for (int qt = 0; qt < 8; ++qt) {
      const int mi = (sp * kN + i0 + 16 * qt + l15) * 2;
      ml[mi] = m_run[qt];
      ml[mi + 1] = l_run[qt];
    }
  }
}

// ---------------------------------------------------------------------------
// Merge 4 key-split NORMALIZED bf16 partials, 4 elements/thread (ushort4):
// h1 = sum_sp w_sp*On_sp, w_sp = e^{m_sp-m} l_sp / sum e^{m_sp-m} l_sp
// ---------------------------------------------------------------------------
__global__ __launch_bounds__(256) void merge_kernel(
    const ushort* __restrict__ Opart, const float* __restrict__ ml,
    float* __restrict__ O)
{
  const size_t base = ((size_t)blockIdx.x * 256 + threadIdx.x) * 4;
  const size_t i = base / kD;   // all 4 elems in same row (kD % 4 == 0)
  float m = ml[i * 2];
#pragma unroll
  for (int sp = 1; sp < SPLITf; ++sp)
    m = fmaxf(m, ml[((size_t)sp * kN + i) * 2]);
  float den = 0.f;
  float acc0 = 0.f, acc1 = 0.f, acc2 = 0.f, acc3 = 0.f;
#pragma unroll
  for (int sp = 0; sp < SPLITf; ++sp) {
    const float e = __expf(ml[((size_t)sp * kN + i) * 2] - m) *
                    ml[((size_t)sp * kN + i) * 2 + 1];
    den += e;
    const ushort4 ov =
        *reinterpret_cast<const ushort4*>(&Opart[(size_t)sp * kND + base]);
    acc0 += e * bf2f(ov.x);
    acc1 += e * bf2f(ov.y);
    acc2 += e * bf2f(ov.z);
    acc3 += e * bf2f(ov.w);
  }
  const float inv = 1.0f / den;
  float4 r;
  r.x = acc0 * inv; r.y = acc1 * inv; r.z = acc2 * inv; r.w = acc3 * inv;
  *reinterpret_cast<float4*>(&O[base]) = r;
}

// ---------------------------------------------------------------------------
// Layer-2: exact matvec chain (parallel versions).
// ---------------------------------------------------------------------------
__global__ __launch_bounds__(64) void qrow_kernel(
    const float* __restrict__ h1, const float* __restrict__ Wq,
    float* __restrict__ q2)
{
  const int j = blockIdx.x;
  const int lane = threadIdx.x;
  const float* hr = h1 + (size_t)(kN - 1) * kD;
  float acc = 0.f;
  for (int d = lane; d < kD; d += 64) acc += hr[d] * Wq[(size_t)j * kD + d];
#pragma unroll
  for (int off = 32; off > 0; off >>= 1) acc += __shfl_xor(acc, off, 64);
  if (lane == 0) q2[j] = acc;
}

// u[d] = sum_k Wk[k][d] * q2[k];  6 blocks x 64 threads (coalesced over d)
__global__ __launch_bounds__(64) void u_kernel(
    const float* __restrict__ Wk, const float* __restrict__ q2,
    float* __restrict__ u)
{
  __shared__ float qs[kD];
  const int t = threadIdx.x;
  const int d = blockIdx.x * 64 + t;
  for (int k = t; k < kD; k += 64) qs[k] = q2[k];
  __syncthreads();
  float acc = 0.f;
  for (int k = 0; k < kD; ++k) acc += Wk[(size_t)k * kD + d] * qs[k];
  u[d] = acc;
}

__global__ __launch_bounds__(256) void logits_kernel(
    const float* __restrict__ h1, const float* __restrict__ u,
    float* __restrict__ lg)
{
  const int wave = threadIdx.x >> 6;
  const int lane = threadIdx.x & 63;
  const int j = blockIdx.x * 4 + wave;
  float acc = 0.f;
#pragma unroll
  for (int t = 0; t < kD / 64; ++t) {
    const int d = lane + t * 64;
    acc += h1[(size_t)j * kD + d] * u[d];
  }
#pragma unroll
  for (int off = 32; off > 0; off >>= 1) acc += __shfl_xor(acc, off, 64);
  if (lane == 0) lg[j] = acc;
}

__global__ __launch_bounds__(1024) void smax_kernel(
    const float* __restrict__ lg, float* __restrict__ wgt)
{
  __shared__ float red[16];
  const int t = threadIdx.x;
  const int wave = t >> 6;
  const int lane = t & 63;
  float v[8];
  float mx = -INFINITY;
#pragma unroll
  for (int s = 0; s < 8; ++s) {
    v[s] = lg[t + 1024 * s];
    mx = fmaxf(mx, v[s]);
  }
#pragma unroll
  for (int off = 32; off > 0; off >>= 1) mx = fmaxf(mx, __shfl_xor(mx, off, 64));
  if (lane == 0) red[wave] = mx;
  __syncthreads();
  if (t == 0) {
    float m = red[0];
    for (int i = 1; i < 16; ++i) m = fmaxf(m, red[i]);
    red[0] = m;
  }
  __syncthreads();
  const float m = red[0];
  __syncthreads();
  float sum = 0.f;
#pragma unroll
  for (int s = 0; s < 8; ++s) {
    v[s] = expf(v[s] - m);
    sum += v[s];
  }
#pragma unroll
  for (int off = 32; off > 0; off >>= 1) sum += __shfl_xor(sum, off, 64);
  if (lane == 0) red[wave] = sum;
  __syncthreads();
  if (t == 0) {
    float S = 0.f;
    for (int i = 0; i < 16; ++i) S += red[i];
    red[0] = S;
  }
  __syncthreads();
  const float invS = 1.0f / red[0];
#pragma unroll
  for (int s = 0; s < 8; ++s) wgt[t + 1024 * s] = v[s] * invS;
}

// part[b][d] = sum_{j in block b's 64 rows} wgt[j] * h1[j][d]; 128 blocks
__global__ __launch_bounds__(384) void wsum_kernel(
    const float* __restrict__ wgt, const float* __restrict__ h1,
    float* __restrict__ part)
{
  __shared__ float wl[64];
  const int b = blockIdx.x;
  const int t = threadIdx.x;
  if (t < 64) wl[t] = wgt[b * 64 + t];
  __syncthreads();
  const float* Hp = h1 + (size_t)b * 64 * kD;
  float acc = 0.f;
  for (int j = 0; j < 64; ++j) acc += wl[j] * Hp[(size_t)j * kD + t];
  part[b * kD + t] = acc;
}

// out = sigmoid( sum_d g[d] * z[d] ),  z[d] = sum_b part[b][d]
// (uses precomputed g = Wv^T ffws; exact identity with the reference chain)
__global__ __launch_bounds__(384) void final3_kernel(
    const float* __restrict__ part, const float* __restrict__ g,
    float* __restrict__ out)
{
  __shared__ float red[6];
  const int t = threadIdx.x;
  const int wave = t >> 6;
  const int lane = t & 63;
  float z = 0.f;
  for (int b = 0; b < 128; ++b) z += part[b * kD + t];
  float val = z * g[t];
#pragma unroll
  for (int off = 32; off > 0; off >>= 1) val += __shfl_xor(val, off, 64);
  if (lane == 0) red[wave] = val;
  __syncthreads();
  if (t == 0) {
    float s = red[0];
    for (int i = 1; i < 6; ++i) s += red[i];
    out[0] = 1.0f / (1.0f + expf(-s));
  }
}

// ---------------------------------------------------------------------------
extern "C" void kernel_launch(void* const* d_in, const int* in_sizes, int n_in,
                              void* d_out, int out_size, void* d_ws, size_t ws_size,
                              hipStream_t stream) {
  const float* x    = (const float*)d_in[0];
  const float* Wq   = (const float*)d_in[1];
  const float* Wk   = (const float*)d_in[2];
  const float* Wv   = (const float*)d_in[3];
  const float* ffws = (const float*)d_in[4];
  float* out = (float*)d_out;
  char* wsb = (char*)d_ws;

  ushort* Qh  = (ushort*)wsb;
  ushort* Kh  = Qh + kND;
  ushort* VTh = Kh + kND;
  ushort* Opart = VTh + kND;                         // bf16 [4][kND]
  float* ml    = (float*)(Opart + (size_t)SPLITf * kND);  // [4][kN][2]
  float* h1    = ml + (size_t)SPLITf * kN * 2;
  float* q2    = h1 + (size_t)kND;
  float* u     = q2 + kD;
  float* lg    = u + kD;
  float* wgt   = lg + kN;
  float* part  = wgt + kN;   // [128][kD]
  float* g     = part + 128 * kD;

  // g = Wv^T ffws (inputs-only; overlaps with proj/flash)
  gv_kernel<<<kD / 64, 64, 0, stream>>>(Wv, ffws, g);
  // layer-1 projections (single pass, 1-term bf16 MFMA)
  proj_mfma<<<dim3(kN / 128, kD / 96), 512, 0, stream>>>(
      x, Wq, Wk, Wv, Qh, Kh, VTh);
  // layer-1 attention
  flash_mfma<<<dim3(SPLITf, kN / 128), 512, 0, stream>>>(
      Qh, Kh, VTh, Opart, ml);
  merge_kernel<<<(kN * kD) / 1024, 256, 0, stream>>>(Opart, ml, h1);
  // layer-2 (exact matvec chain)
  qrow_kernel<<<kD, 64, 0, stream>>>(h1, Wq, q2);
  u_kernel<<<kD / 64, 64, 0, stream>>>(Wk, q2, u);
  logits_kernel<<<kN / 4, 256, 0, stream>>>(h1, u, lg);
  smax_kernel<<<1, 1024, 0, stream>>>(lg, wgt);
  wsum_kernel<<<kN / 64, 384, 0, stream>>>(wgt, h1, part);
  final3_kernel<<<1, 384, 0, stream>>>(part, g, out);
}

// Round 20
// 256.461 us; speedup vs baseline: 1.0165x; 1.0165x over previous
//
#include <hip/hip_runtime.h>
#include <hip/hip_bf16.h>
#include <math.h>

static constexpr int kN = 8192;
static constexpr int kD = 384;
static constexpr int kND = kN * kD;

typedef __attribute__((ext_vector_type(8))) short short8;
typedef __attribute__((ext_vector_type(4))) float f32x4;

// ---- bf16 helpers (bit-exact RNE) ----
__device__ __forceinline__ ushort f2bf(float f) {
  union { float f; unsigned int i; } cv; cv.f = f;
  unsigned int lsb = (cv.i >> 16) & 1u;
  unsigned int r = cv.i + 0x7fffu + lsb;
  return (ushort)(r >> 16);
}
__device__ __forceinline__ float bf2f(ushort u) {
  union { unsigned int i; float f; } cv; cv.i = ((unsigned int)u) << 16;
  return cv.f;
}
__device__ __forceinline__ f32x4 mfma_bf16(short8 a, short8 b, f32x4 c) {
  return __builtin_amdgcn_mfma_f32_16x16x32_bf16(a, b, c, 0, 0, 0);
}
// LDS-only barrier: drains LDS ops for cross-wave visibility; in-flight
// global loads survive (no vmcnt(0) drain).
__device__ __forceinline__ void bar_lds() {
  asm volatile("s_waitcnt lgkmcnt(0)" ::: "memory");
  __builtin_amdgcn_s_barrier();
}

// ---------------------------------------------------------------------------
// MFMA projection, 1-term bf16 (outputs are rounded to bf16 anyway).
// Single pass over x:
//   Qh = bf16(x@Wq^T), Kh = bf16(x@Wk^T)   (row-major [N][D])
//   VTh = bf16((x@Wv^T)^T)                  ([D][N])
// Block: 512 thr (8 waves), tile 128 rows x 96 cols, d-loop 12x32.
// LDS: XH 128x32 + WH 3x96x32 bf16 = 26 KB.
// ---------------------------------------------------------------------------
__global__ __launch_bounds__(512) void proj_mfma(
    const float* __restrict__ x, const float* __restrict__ Wq,
    const float* __restrict__ Wk, const float* __restrict__ Wv,
    ushort* __restrict__ Qh, ushort* __restrict__ Kh,
    ushort* __restrict__ VTh)
{
  __shared__ ushort XH[128 * 32];
  __shared__ ushort WH[3][96 * 32];

  const int tid = threadIdx.x;
  const int w = tid >> 6;
  const int lane = tid & 63;
  const int l15 = lane & 15;
  const int hi4 = lane >> 4;
  const int i0 = blockIdx.x * 128;
  const int j0 = blockIdx.y * 96;
  const float* Wm[3] = {Wq, Wk, Wv};

  const f32x4 zf = {0.f, 0.f, 0.f, 0.f};
  f32x4 acc[3][6];
#pragma unroll
  for (int m = 0; m < 3; ++m)
#pragma unroll
    for (int ct = 0; ct < 6; ++ct) acc[m][ct] = zf;

  const int xrow = tid >> 2;
  const int xc8 = (tid & 3) * 8;

  for (int dc = 0; dc < 12; ++dc) {
    const int d0 = dc * 32;
    {
      const float* src = x + (size_t)(i0 + xrow) * kD + d0 + xc8;
      const float4 v0 = *reinterpret_cast<const float4*>(src);
      const float4 v1 = *reinterpret_cast<const float4*>(src + 4);
      const float vs[8] = {v0.x, v0.y, v0.z, v0.w, v1.x, v1.y, v1.z, v1.w};
      ushort hh[8];
#pragma unroll
      for (int j = 0; j < 8; ++j) hh[j] = f2bf(vs[j]);
      *reinterpret_cast<uint4*>(&XH[xrow * 32 + xc8]) =
          *reinterpret_cast<const uint4*>(hh);
    }
    if (tid < 384) {
#pragma unroll
      for (int m = 0; m < 3; ++m) {
        const float* src = Wm[m] + (size_t)(j0 + xrow) * kD + d0 + xc8;
        const float4 v0 = *reinterpret_cast<const float4*>(src);
        const float4 v1 = *reinterpret_cast<const float4*>(src + 4);
        const float vs[8] = {v0.x, v0.y, v0.z, v0.w, v1.x, v1.y, v1.z, v1.w};
        ushort hh[8];
#pragma unroll
        for (int j = 0; j < 8; ++j) hh[j] = f2bf(vs[j]);
        *reinterpret_cast<uint4*>(&WH[m][xrow * 32 + xc8]) =
            *reinterpret_cast<const uint4*>(hh);
      }
    }
    __syncthreads();
    const short8 xa = *reinterpret_cast<const short8*>(
        &XH[(16 * w + l15) * 32 + 8 * hi4]);
#pragma unroll
    for (int m = 0; m < 3; ++m) {
#pragma unroll
      for (int ct = 0; ct < 6; ++ct) {
        const short8 wh = *reinterpret_cast<const short8*>(
            &WH[m][(16 * ct + l15) * 32 + 8 * hi4]);
        acc[m][ct] = mfma_bf16(xa, wh, acc[m][ct]);
      }
    }
    __syncthreads();
  }

#pragma unroll
  for (int ct = 0; ct < 6; ++ct)
#pragma unroll
    for (int r = 0; r < 4; ++r) {
      const size_t oi =
          (size_t)(i0 + 16 * w + 4 * hi4 + r) * kD + j0 + 16 * ct + l15;
      Qh[oi] = f2bf(acc[0][ct][r]);
      Kh[oi] = f2bf(acc[1][ct][r]);
    }
#pragma unroll
  for (int ct = 0; ct < 6; ++ct) {
    ushort4 h;
    ushort* hp = &h.x;
#pragma unroll
    for (int r = 0; r < 4; ++r) hp[r] = f2bf(acc[2][ct][r]);
    *reinterpret_cast<ushort4*>(
        &VTh[(size_t)(j0 + 16 * ct + l15) * kN + i0 + 16 * w + 4 * hi4]) = h;
  }
}

// ---------------------------------------------------------------------------
// MFMA flash attention v16 (best measured: 180.5 us, no spill): r11 schedule
// with vv issued IMMEDIATELY after the S-MFMAs (ka dead there -> register
// peak unchanged), so the V stream hides under max-reduce + B1 + softmax.
// BM=128, 512 threads (8 waves), SPLIT=4 -> grid (4,64)=256 blocks, 1/CU.
// Pure-bf16 S = kh*qh; P hi LDS; vectorized MLB; normalized bf16 Opart.
// Only ONE 12-frag stream buffer live at a time (128 arch-VGPR half;
// o[96]+sacc[32] fill the 128-AGPR half exactly).
// LDS: Qh 100K | P 34.8K | MLB 8K = 143K.
// ---------------------------------------------------------------------------
static constexpr int SPLITf = 4;
static constexpr int KEYSf = kN / SPLITf;   // 2048
static constexpr int NTIL = KEYSf / 128;    // 16

static constexpr int OFF_QH = 0;        // ushort offsets into LDSU
static constexpr int OFF_P  = 50176;    // 128*392

__global__ __launch_bounds__(512, 2) void flash_mfma(
    const ushort* __restrict__ Qh,
    const ushort* __restrict__ Kh,
    const ushort* __restrict__ VTh,
    ushort* __restrict__ Opart, float* __restrict__ ml)
{
  __shared__ ushort LDSU[67584];   // 135168 B (Qh 128x392 | P 128x136)
  __shared__ float MLB[2048];      // m: [(row)*8+w], l: 1024 + same

  const int tid = threadIdx.x;
  const int w = tid >> 6;
  const int lane = tid & 63;
  const int l15 = lane & 15;
  const int hi4 = lane >> 4;
  const int sp = blockIdx.x;
  const int i0 = blockIdx.y * 128;
  const int kg0 = sp * KEYSf;

  // ---- stage Q-hi once: 128 rows, stride 392 ushorts ----
  {
    const int row = tid >> 2;            // 0..127
    const int sg = (tid & 3) * 96;       // 96 ushorts = 12 x uint4
    const ushort* sh = Qh + (size_t)(i0 + row) * kD + sg;
    ushort* dh = LDSU + OFF_QH + row * 392 + sg;
#pragma unroll
    for (int u = 0; u < 12; ++u)
      *reinterpret_cast<uint4*>(dh + 8 * u) =
          *reinterpret_cast<const uint4*>(sh + 8 * u);
  }

  const f32x4 zf = {0.f, 0.f, 0.f, 0.f};
  f32x4 o[8][3];
#pragma unroll
  for (int qt = 0; qt < 8; ++qt)
#pragma unroll
    for (int c = 0; c < 3; ++c) o[qt][c] = zf;
  float m_run[8], l_run[8];
#pragma unroll
  for (int qt = 0; qt < 8; ++qt) { m_run[qt] = -INFINITY; l_run[qt] = 0.f; }

  __syncthreads();   // Q staged

  for (int kb = 0; kb < NTIL; ++kb) {
    const int kg = kg0 + kb * 128;

    // ---- S phase: K hi batch-loaded (12 frags), Q hi from LDS ----
    f32x4 sacc[8];
#pragma unroll
    for (int qt = 0; qt < 8; ++qt) sacc[qt] = zf;
    const size_t kbase = (size_t)(kg + 16 * w + l15) * kD + 8 * hi4;
    short8 ka[12];
#pragma unroll
    for (int ks = 0; ks < 12; ++ks)
      ka[ks] = *reinterpret_cast<const short8*>(Kh + kbase + 32 * ks);
    __builtin_amdgcn_sched_barrier(0);   // keep loads batched above MFMAs
#pragma unroll
    for (int ks = 0; ks < 12; ++ks) {
      const int d0 = 32 * ks;
#pragma unroll
      for (int qt = 0; qt < 8; ++qt) {
        const short8 qh = *reinterpret_cast<const short8*>(
            LDSU + OFF_QH + (16 * qt + l15) * 392 + d0 + 8 * hi4);
        sacc[qt] = mfma_bf16(ka[ks], qh, sacc[qt]);
      }
    }
    __builtin_amdgcn_sched_barrier(0);

    // ---- V-EARLIEST: issue 12 V-frag loads right after S (ka dead) ----
    // Stream hides under max-reduce + B1 barrier wait + softmax.
    short8 vv[12];
#pragma unroll
    for (int c = 0; c < 3; ++c)
#pragma unroll
      for (int kv = 0; kv < 4; ++kv)
        vv[c * 4 + kv] = *reinterpret_cast<const short8*>(
            VTh + (size_t)(48 * w + 16 * c + l15) * kN + kg + 32 * kv + 8 * hi4);
    __builtin_amdgcn_sched_barrier(0);

    // ---- per-wave tile max -> MLB (vector-friendly layout) ----
#pragma unroll
    for (int qt = 0; qt < 8; ++qt) {
      float mt = fmaxf(fmaxf(sacc[qt][0], sacc[qt][1]),
                       fmaxf(sacc[qt][2], sacc[qt][3]));
      mt = fmaxf(mt, __shfl_xor(mt, 16, 64));
      mt = fmaxf(mt, __shfl_xor(mt, 32, 64));
      if (lane < 16) MLB[(qt * 16 + l15) * 8 + w] = mt;
    }
    bar_lds();  // B1: all waves' m published

    // ---- softmax (vectorized MLB reads) ----
    float sc[8];
#pragma unroll
    for (int qt = 0; qt < 8; ++qt) {
      const float4 ma =
          *reinterpret_cast<const float4*>(&MLB[(qt * 16 + l15) * 8]);
      const float4 mb =
          *reinterpret_cast<const float4*>(&MLB[(qt * 16 + l15) * 8 + 4]);
      const float Mt = fmaxf(fmaxf(fmaxf(ma.x, ma.y), fmaxf(ma.z, ma.w)),
                             fmaxf(fmaxf(mb.x, mb.y), fmaxf(mb.z, mb.w)));
      const float mnew = fmaxf(m_run[qt], Mt);
      sc[qt] = __expf(m_run[qt] - mnew);
      m_run[qt] = mnew;
      const float p0 = __expf(sacc[qt][0] - mnew);
      const float p1 = __expf(sacc[qt][1] - mnew);
      const float p2 = __expf(sacc[qt][2] - mnew);
      const float p3 = __expf(sacc[qt][3] - mnew);
      float ls = (p0 + p1) + (p2 + p3);
      ls += __shfl_xor(ls, 16, 64);
      ls += __shfl_xor(ls, 32, 64);
      if (lane < 16) MLB[1024 + (qt * 16 + l15) * 8 + w] = ls;
      // pack P -> bf16 hi, one b64 write
      uint2 HH;
      HH.x = (unsigned int)f2bf(p0) | ((unsigned int)f2bf(p1) << 16);
      HH.y = (unsigned int)f2bf(p2) | ((unsigned int)f2bf(p3) << 16);
      const int pi = (16 * qt + l15) * 136 + 16 * w + 4 * hi4;
      *reinterpret_cast<uint2*>(LDSU + OFF_P + pi) = HH;
      // rescale O (row of o = qrow 16qt+4*hi4+r)
#pragma unroll
      for (int r = 0; r < 4; ++r) {
        const float scr_ = __shfl(sc[qt], 4 * hi4 + r, 64);
#pragma unroll
        for (int c = 0; c < 3; ++c) o[qt][c][r] *= scr_;
      }
    }
    bar_lds();  // B2: P + l published
#pragma unroll
    for (int qt = 0; qt < 8; ++qt) {
      const float4 la =
          *reinterpret_cast<const float4*>(&MLB[1024 + (qt * 16 + l15) * 8]);
      const float4 lb =
          *reinterpret_cast<const float4*>(&MLB[1024 + (qt * 16 + l15) * 8 + 4]);
      const float ls = ((la.x + la.y) + (la.z + la.w)) +
                       ((lb.x + lb.y) + (lb.z + lb.w));
      l_run[qt] = l_run[qt] * sc[qt] + ls;
    }

    // ---- PV: 96 MFMAs on prefetched vv ----
#pragma unroll
    for (int kv = 0; kv < 4; ++kv) {
      short8 pf[8];
#pragma unroll
      for (int qt = 0; qt < 8; ++qt)
        pf[qt] = *reinterpret_cast<const short8*>(
            LDSU + OFF_P + (16 * qt + l15) * 136 + 32 * kv + 8 * hi4);
#pragma unroll
      for (int c = 0; c < 3; ++c) {
#pragma unroll
        for (int qt = 0; qt < 8; ++qt)
          o[qt][c] = mfma_bf16(pf[qt], vv[c * 4 + kv], o[qt][c]);
      }
    }
  }

  // ---- write NORMALIZED bf16 partials + (m,l) ----
#pragma unroll
  for (int qt = 0; qt < 8; ++qt) {
    const float linv = 1.0f / l_run[qt];
#pragma unroll
    for (int r = 0; r < 4; ++r) {
      const float lr = __shfl(linv, 4 * hi4 + r, 64);
#pragma unroll
      for (int c = 0; c < 3; ++c)
        Opart[(size_t)sp * kND + (i0 + 16 * qt + 4 * hi4 + r) * kD +
              48 * w + 16 * c + l15] = f2bf(o[qt][c][r] * lr);
    }
  }
  if (w == 0 && lane < 16) {
#pragma unroll
    for (int qt = 0; qt < 8; ++qt) {
      const int mi = (sp * kN + i0 + 16 * qt + l15) * 2;
      ml[mi] = m_run[qt];
      ml[mi + 1] = l_run[qt];
    }
  }
}

// ---------------------------------------------------------------------------
// Merge 4 key-split NORMALIZED bf16 partials, 4 elements/thread (ushort4):
// h1 = sum_sp w_sp*On_sp, w_sp = e^{m_sp-m} l_sp / sum e^{m_sp-m} l_sp
// ---------------------------------------------------------------------------
__global__ __launch_bounds__(256) void merge_kernel(
    const ushort* __restrict__ Opart, const float* __restrict__ ml,
    float* __restrict__ O)
{
  const size_t base = ((size_t)blockIdx.x * 256 + threadIdx.x) * 4;
  const size_t i = base / kD;   // all 4 elems in same row (kD % 4 == 0)
  float m = ml[i * 2];
#pragma unroll
  for (int sp = 1; sp < SPLITf; ++sp)
    m = fmaxf(m, ml[((size_t)sp * kN + i) * 2]);
  float den = 0.f;
  float acc0 = 0.f, acc1 = 0.f, acc2 = 0.f, acc3 = 0.f;
#pragma unroll
  for (int sp = 0; sp < SPLITf; ++sp) {
    const float e = __expf(ml[((size_t)sp * kN + i) * 2] - m) *
                    ml[((size_t)sp * kN + i) * 2 + 1];
    den += e;
    const ushort4 ov =
        *reinterpret_cast<const ushort4*>(&Opart[(size_t)sp * kND + base]);
    acc0 += e * bf2f(ov.x);
    acc1 += e * bf2f(ov.y);
    acc2 += e * bf2f(ov.z);
    acc3 += e * bf2f(ov.w);
  }
  const float inv = 1.0f / den;
  float4 r;
  r.x = acc0 * inv; r.y = acc1 * inv; r.z = acc2 * inv; r.w = acc3 * inv;
  *reinterpret_cast<float4*>(&O[base]) = r;
}

// ---------------------------------------------------------------------------
// Layer-2: exact matvec chain (parallel versions).
// ---------------------------------------------------------------------------
__global__ __launch_bounds__(64) void qrow_kernel(
    const float* __restrict__ h1, const float* __restrict__ Wq,
    float* __restrict__ q2)
{
  const int j = blockIdx.x;
  const int lane = threadIdx.x;
  const float* hr = h1 + (size_t)(kN - 1) * kD;
  float acc = 0.f;
  for (int d = lane; d < kD; d += 64) acc += hr[d] * Wq[(size_t)j * kD + d];
#pragma unroll
  for (int off = 32; off > 0; off >>= 1) acc += __shfl_xor(acc, off, 64);
  if (lane == 0) q2[j] = acc;
}

// u[d] = sum_k Wk[k][d] * q2[k];  6 blocks x 64 threads (coalesced over d)
__global__ __launch_bounds__(64) void u_kernel(
    const float* __restrict__ Wk, const float* __restrict__ q2,
    float* __restrict__ u)
{
  __shared__ float qs[kD];
  const int t = threadIdx.x;
  const int d = blockIdx.x * 64 + t;
  for (int k = t; k < kD; k += 64) qs[k] = q2[k];
  __syncthreads();
  float acc = 0.f;
  for (int k = 0; k < kD; ++k) acc += Wk[(size_t)k * kD + d] * qs[k];
  u[d] = acc;
}

__global__ __launch_bounds__(256) void logits_kernel(
    const float* __restrict__ h1, const float* __restrict__ u,
    float* __restrict__ lg)
{
  const int wave = threadIdx.x >> 6;
  const int lane = threadIdx.x & 63;
  const int j = blockIdx.x * 4 + wave;
  float acc = 0.f;
#pragma unroll
  for (int t = 0; t < kD / 64; ++t) {
    const int d = lane + t * 64;
    acc += h1[(size_t)j * kD + d] * u[d];
  }
#pragma unroll
  for (int off = 32; off > 0; off >>= 1) acc += __shfl_xor(acc, off, 64);
  if (lane == 0) lg[j] = acc;
}

__global__ __launch_bounds__(1024) void smax_kernel(
    const float* __restrict__ lg, float* __restrict__ wgt)
{
  __shared__ float red[16];
  const int t = threadIdx.x;
  const int wave = t >> 6;
  const int lane = t & 63;
  float v[8];
  float mx = -INFINITY;
#pragma unroll
  for (int s = 0; s < 8; ++s) {
    v[s] = lg[t + 1024 * s];
    mx = fmaxf(mx, v[s]);
  }
#pragma unroll
  for (int off = 32; off > 0; off >>= 1) mx = fmaxf(mx, __shfl_xor(mx, off, 64));
  if (lane == 0) red[wave] = mx;
  __syncthreads();
  if (t == 0) {
    float m = red[0];
    for (int i = 1; i < 16; ++i) m = fmaxf(m, red[i]);
    red[0] = m;
  }
  __syncthreads();
  const float m = red[0];
  __syncthreads();
  float sum = 0.f;
#pragma unroll
  for (int s = 0; s < 8; ++s) {
    v[s] = expf(v[s] - m);
    sum += v[s];
  }
#pragma unroll
  for (int off = 32; off > 0; off >>= 1) sum += __shfl_xor(sum, off, 64);
  if (lane == 0) red[wave] = sum;
  __syncthreads();
  if (t == 0) {
    float S = 0.f;
    for (int i = 0; i < 16; ++i) S += red[i];
    red[0] = S;
  }
  __syncthreads();
  const float invS = 1.0f / red[0];
#pragma unroll
  for (int s = 0; s < 8; ++s) wgt[t + 1024 * s] = v[s] * invS;
}

// part[b][d] = sum_{j in block b's 64 rows} wgt[j] * h1[j][d]; 128 blocks
__global__ __launch_bounds__(384) void wsum_kernel(
    const float* __restrict__ wgt, const float* __restrict__ h1,
    float* __restrict__ part)
{
  __shared__ float wl[64];
  const int b = blockIdx.x;
  const int t = threadIdx.x;
  if (t < 64) wl[t] = wgt[b * 64 + t];
  __syncthreads();
  const float* Hp = h1 + (size_t)b * 64 * kD;
  float acc = 0.f;
  for (int j = 0; j < 64; ++j) acc += wl[j] * Hp[(size_t)j * kD + t];
  part[b * kD + t] = acc;
}

__global__ __launch_bounds__(384) void final2_kernel(
    const float* __restrict__ part, const float* __restrict__ Wv,
    const float* __restrict__ ffws, float* __restrict__ out)
{
  __shared__ float zs[kD];
  __shared__ float red[6];
  const int t = threadIdx.x;
  const int wave = t >> 6;
  const int lane = t & 63;
  float z = 0.f;
  for (int b = 0; b < 128; ++b) z += part[b * kD + t];
  zs[t] = z;
  __syncthreads();
  float zv = 0.f;
  for (int k = 0; k < kD; ++k) zv += Wv[(size_t)t * kD + k] * zs[k];
  float val = zv * ffws[t];
#pragma unroll
  for (int off = 32; off > 0; off >>= 1) val += __shfl_xor(val, off, 64);
  if (lane == 0) red[wave] = val;
  __syncthreads();
  if (t == 0) {
    float s = red[0];
    for (int i = 1; i < 6; ++i) s += red[i];
    out[0] = 1.0f / (1.0f + expf(-s));
  }
}

// ---------------------------------------------------------------------------
extern "C" void kernel_launch(void* const* d_in, const int* in_sizes, int n_in,
                              void* d_out, int out_size, void* d_ws, size_t ws_size,
                              hipStream_t stream) {
  const float* x    = (const float*)d_in[0];
  const float* Wq   = (const float*)d_in[1];
  const float* Wk   = (const float*)d_in[2];
  const float* Wv   = (const float*)d_in[3];
  const float* ffws = (const float*)d_in[4];
  float* out = (float*)d_out;
  char* wsb = (char*)d_ws;

  ushort* Qh  = (ushort*)wsb;
  ushort* Kh  = Qh + kND;
  ushort* VTh = Kh + kND;
  ushort* Opart = VTh + kND;                         // bf16 [4][kND]
  float* ml    = (float*)(Opart + (size_t)SPLITf * kND);  // [4][kN][2]
  float* h1    = ml + (size_t)SPLITf * kN * 2;
  float* q2    = h1 + (size_t)kND;
  float* u     = q2 + kD;
  float* lg    = u + kD;
  float* wgt   = lg + kN;
  float* part  = wgt + kN;   // [128][kD]

  // layer-1 projections (single pass, 1-term bf16 MFMA)
  proj_mfma<<<dim3(kN / 128, kD / 96), 512, 0, stream>>>(
      x, Wq, Wk, Wv, Qh, Kh, VTh);
  // layer-1 attention
  flash_mfma<<<dim3(SPLITf, kN / 128), 512, 0, stream>>>(
      Qh, Kh, VTh, Opart, ml);
  merge_kernel<<<(kN * kD) / 1024, 256, 0, stream>>>(Opart, ml, h1);
  // layer-2 (exact matvec chain)
  qrow_kernel<<<kD, 64, 0, stream>>>(h1, Wq, q2);
  u_kernel<<<kD / 64, 64, 0, stream>>>(Wk, q2, u);
  logits_kernel<<<kN / 4, 256, 0, stream>>>(h1, u, lg);
  smax_kernel<<<1, 1024, 0, stream>>>(lg, wgt);
  wsum_kernel<<<kN / 64, 384, 0, stream>>>(wgt, h1, part);
  final2_kernel<<<1, 384, 0, stream>>>(part, Wv, ffws, out);
}